// Round 2
// baseline (958.289 us; speedup 1.0000x reference)
//
#include <hip/hip_runtime.h>

// ---------------------------------------------------------------------------
// BaseGAT: per-edge attention logit -> per-dst segment softmax ->
//          alpha-weighted message scattered into [N, T, 160] by (dst, et).
// Split:   z_edge @ W == h[src]·W[0:64] + e·W[64:96] + h[dst]·W[96:160]
//          so node dots are precomputed once per node.
// ---------------------------------------------------------------------------

__device__ __forceinline__ unsigned encf(float x) {
    unsigned u = __float_as_uint(x);
    // monotone map float -> unsigned (total order); memset-0 == minimum
    return (u & 0x80000000u) ? ~u : (u | 0x80000000u);
}
__device__ __forceinline__ float decf(unsigned u) {
    return (u & 0x80000000u) ? __uint_as_float(u & 0x7FFFFFFFu)
                             : __uint_as_float(~u);
}

// K1: p1[n] = h[n]·W[0:64], p2[n] = h[n]·W[96:160]; one wave (64 lanes)/node
__global__ void node_dots(const float* __restrict__ h, const float* __restrict__ W,
                          float* __restrict__ p1, float* __restrict__ p2, int N) {
    int wave = (int)((blockIdx.x * (size_t)blockDim.x + threadIdx.x) >> 6);
    int lane = threadIdx.x & 63;
    if (wave >= N) return;
    float x  = h[(size_t)wave * 64 + lane];
    float v1 = x * W[lane];
    float v2 = x * W[96 + lane];
    #pragma unroll
    for (int o = 32; o; o >>= 1) {
        v1 += __shfl_xor(v1, o);
        v2 += __shfl_xor(v2, o);
    }
    if (lane == 0) { p1[wave] = v1; p2[wave] = v2; }
}

// K2: a[i] = leaky_relu(p1[src] + e_i·W[64:96] + p2[dst]); atomicMax into m[dst]
__global__ void edge_att(const float* __restrict__ e, const float* __restrict__ W,
                         const int* __restrict__ src, const int* __restrict__ dst,
                         const float* __restrict__ p1, const float* __restrict__ p2,
                         float* __restrict__ a, unsigned* __restrict__ m, int E) {
    int i = (int)(blockIdx.x * (size_t)blockDim.x + threadIdx.x);
    if (i >= E) return;
    const float4* er = (const float4*)(e + (size_t)i * 32);
    float acc = 0.f;
    #pragma unroll
    for (int j = 0; j < 8; ++j) {
        float4 v = er[j];
        acc += v.x * W[64 + 4 * j + 0] + v.y * W[64 + 4 * j + 1]
             + v.z * W[64 + 4 * j + 2] + v.w * W[64 + 4 * j + 3];
    }
    int d = dst[i];
    float av = p1[src[i]] + acc + p2[d];
    av = (av > 0.f) ? av : 0.01f * av;   // leaky_relu, slope 0.01
    a[i] = av;
    atomicMax(&m[d], encf(av));
}

// K3: ex = exp(a - m[dst]); s[dst] += ex; a[i] <- ex (in place, for K4)
__global__ void edge_exp(float* __restrict__ a, const int* __restrict__ dst,
                         const unsigned* __restrict__ m, float* __restrict__ s, int E) {
    int i = (int)(blockIdx.x * (size_t)blockDim.x + threadIdx.x);
    if (i >= E) return;
    int d = dst[i];
    float ex = __expf(a[i] - decf(m[d]));
    a[i] = ex;
    atomicAdd(&s[d], ex);
}

// K4: one wave per edge; alpha = ex/s[dst]; scatter alpha*[h_src | e | h_dst]
__global__ void scatter(const float* __restrict__ h, const float* __restrict__ e,
                        const float* __restrict__ a, const int* __restrict__ src,
                        const int* __restrict__ dst, const int* __restrict__ et,
                        const float* __restrict__ s,
                        float* __restrict__ out, int E, int T) {
    size_t gid = blockIdx.x * (size_t)blockDim.x + threadIdx.x;
    int wave = (int)(gid >> 6);
    int lane = (int)(gid & 63);
    if (wave >= E) return;
    int sN = src[wave], dN = dst[wave], t = et[wave];
    // same-address loads broadcast across the wave
    float alpha = a[wave] / s[dN];
    float* o = out + ((size_t)dN * T + t) * 160;
    atomicAdd(o + lane,      alpha * h[(size_t)sN * 64 + lane]);
    if (lane < 32)
        atomicAdd(o + 64 + lane, alpha * e[(size_t)wave * 32 + lane]);
    atomicAdd(o + 96 + lane, alpha * h[(size_t)dN * 64 + lane]);
}

extern "C" void kernel_launch(void* const* d_in, const int* in_sizes, int n_in,
                              void* d_out, int out_size, void* d_ws, size_t ws_size,
                              hipStream_t stream) {
    const float* h   = (const float*)d_in[0];
    const float* e   = (const float*)d_in[1];
    const float* W   = (const float*)d_in[2];
    const int*   src = (const int*)d_in[3];
    const int*   dst = (const int*)d_in[4];
    const int*   et  = (const int*)d_in[5];

    const int N = in_sizes[0] / 64;          // 50000
    const int E = in_sizes[1] / 32;          // 800000
    const int T = (int)((out_size - (size_t)E * 32) / ((size_t)N * 160)); // 8

    // workspace layout (floats): p1[N] | p2[N] | a[E] | m[N] (uint) | s[N]
    float*    ws = (float*)d_ws;
    float*    p1 = ws;
    float*    p2 = ws + N;
    float*    a  = ws + 2 * (size_t)N;
    unsigned* m  = (unsigned*)(ws + 2 * (size_t)N + E);
    float*    s  = ws + 3 * (size_t)N + E;

    const size_t hout_elems = (size_t)N * T * 160;

    // zero h_out (d_out is poisoned 0xAA before every replay) + copy e tail
    hipMemsetAsync(d_out, 0, hout_elems * sizeof(float), stream);
    hipMemcpyAsync((float*)d_out + hout_elems, e, (size_t)E * 32 * sizeof(float),
                   hipMemcpyDeviceToDevice, stream);
    // m (encoded -inf == 0) and s (0.0f) are contiguous: one memset
    hipMemsetAsync(m, 0, (size_t)2 * N * sizeof(unsigned), stream);

    node_dots<<<dim3((N * 64 + 255) / 256), dim3(256), 0, stream>>>(h, W, p1, p2, N);
    edge_att <<<dim3((E + 255) / 256),      dim3(256), 0, stream>>>(e, W, src, dst, p1, p2, a, m, E);
    edge_exp <<<dim3((E + 255) / 256),      dim3(256), 0, stream>>>(a, dst, m, s, E);
    scatter  <<<dim3((E + 3) / 4),          dim3(256), 0, stream>>>(h, e, a, src, dst, et, s,
                                                                    (float*)d_out, E, T);
}